// Round 2
// baseline (1336.685 us; speedup 1.0000x reference)
//
#include <hip/hip_runtime.h>
#include <math.h>

constexpr int Nn = 64, Cc = 64, Tt = 300, Vv = 25, Ff = 64;
constexpr int TP = Tt / 2;   // 150 t-pairs per n
constexpr int VP = 28;       // V padded to multiple of 4 for float4 tiles
constexpr int HS = 68;       // hs row stride (floats): 68 % 32 == 4 -> conflict-light
constexpr float ALPHA = 0.2f;
constexpr float NEG_INF = -9.0e15f;

__global__ __launch_bounds__(256, 3) void gat_kernel(
    const float* __restrict__ x,    // (N,C,T,V)
    const int*   __restrict__ adj,  // (V,V)
    const float* __restrict__ W,    // (C,F)
    const float* __restrict__ a,    // (2F,1)
    float* __restrict__ out)        // (N,F,T,V)
{
    __shared__ float Ws[Cc][Ff];            // 16384 B
    __shared__ float xs[2][Cc][VP];         // 14336 B (pad v=25..27 zeroed)
    __shared__ float hs[2][VP][HS];         // 15232 B
    __shared__ float attT[2][Vv][VP];       // 5600 B  (att transposed: [j][i])
    __shared__ float f1s[2][Vv], f2s[2][Vv];
    __shared__ float a1s[Ff], a2s[Ff];
    __shared__ unsigned adjm[Vv];           // adjacency rows as bitmasks

    const int tid = threadIdx.x;
    const int blk = blockIdx.x;             // n*TP + tp
    const int n = blk / TP, tp = blk - n * TP;
    const int t0 = tp * 2;

    // ---- staging ----
    for (int o = tid; o < Cc * Ff; o += 256) (&Ws[0][0])[o] = W[o];
    {
        const float* xb = x + (size_t)n * Cc * Tt * Vv + (size_t)t0 * Vv;
        // o = c*50 + p*25 + v : 50-float contiguous global runs per c
        for (int o = tid; o < Cc * 2 * Vv; o += 256) {
            int c = o / (2 * Vv);
            int r = o - c * 2 * Vv;           // p*25+v
            int p = r / Vv, v = r - p * Vv;
            xs[p][c][v] = xb[(size_t)c * (Tt * Vv) + r];
        }
        for (int o = tid; o < 2 * Cc * (VP - Vv); o += 256) {   // zero the pad
            int p = o / (Cc * (VP - Vv));
            int r = o - p * Cc * (VP - Vv);
            int c = r / (VP - Vv), v = Vv + (r - c * (VP - Vv));
            xs[p][c][v] = 0.f;
        }
    }
    if (tid < Ff) { a1s[tid] = a[tid]; a2s[tid] = a[Ff + tid]; }
    else if (tid >= 128 && tid < 128 + Vv) {
        int i = tid - 128; unsigned m = 0;
        for (int j = 0; j < Vv; ++j) m |= (adj[i * Vv + j] > 0 ? 1u : 0u) << j;
        adjm[i] = m;
    }
    __syncthreads();

    const int p  = tid >> 7;        // problem 0/1 (t = t0+p)
    const int l  = tid & 127;
    const int f4 = l & 15;          // f-tile: 4 floats at 4*f4
    const int vg = l >> 4;          // 0..7; vg<7 active (v-tile 4 at 4*vg)
    const int v0 = vg * 4;

    // ---- Phase B: h[v][f] = sum_c x[c][v]*W[c][f]; 4v x 4f per thread ----
    if (vg < 7) {
        float4 acc0{0,0,0,0}, acc1{0,0,0,0}, acc2{0,0,0,0}, acc3{0,0,0,0};
        for (int c = 0; c < Cc; ++c) {
            const float4 w  = *(const float4*)&Ws[c][f4 * 4];
            const float4 xv = *(const float4*)&xs[p][c][v0];
            acc0.x += xv.x * w.x; acc0.y += xv.x * w.y; acc0.z += xv.x * w.z; acc0.w += xv.x * w.w;
            acc1.x += xv.y * w.x; acc1.y += xv.y * w.y; acc1.z += xv.y * w.z; acc1.w += xv.y * w.w;
            acc2.x += xv.z * w.x; acc2.y += xv.z * w.y; acc2.z += xv.z * w.z; acc2.w += xv.z * w.w;
            acc3.x += xv.w * w.x; acc3.y += xv.w * w.y; acc3.z += xv.w * w.z; acc3.w += xv.w * w.w;
        }
        *(float4*)&hs[p][v0 + 0][f4 * 4] = acc0;
        *(float4*)&hs[p][v0 + 1][f4 * 4] = acc1;
        *(float4*)&hs[p][v0 + 2][f4 * 4] = acc2;
        *(float4*)&hs[p][v0 + 3][f4 * 4] = acc3;
    }
    __syncthreads();

    // ---- Phase C: f1[i]=h[i,:]·a1, f2[i]=h[i,:]·a2 (50 threads/problem) ----
    if (l < 2 * Vv) {
        const int i = (l < Vv) ? l : l - Vv;
        const float* av = (l < Vv) ? a1s : a2s;
        float s = 0.f;
        #pragma unroll
        for (int q = 0; q < Ff / 4; ++q) {
            float4 h4 = *(const float4*)&hs[p][i][q * 4];
            float4 a4 = *(const float4*)&av[q * 4];
            s += h4.x * a4.x + h4.y * a4.y + h4.z * a4.z + h4.w * a4.w;
        }
        if (l < Vv) f1s[p][i] = s; else f2s[p][i] = s;
    }
    __syncthreads();

    // ---- Phase D: masked leaky-relu + softmax row i; write attT[j][i] ----
    if (l < Vv) {
        const int i = l;
        const float fi = f1s[p][i];
        const unsigned m = adjm[i];
        float ev[Vv];
        float mx = -INFINITY;
        #pragma unroll
        for (int j = 0; j < Vv; ++j) {
            float z = fi + f2s[p][j];
            z = (z > 0.f) ? z : ALPHA * z;         // leaky_relu BEFORE mask
            z = ((m >> j) & 1u) ? z : NEG_INF;
            ev[j] = z; mx = fmaxf(mx, z);
        }
        float s = 0.f;
        #pragma unroll
        for (int j = 0; j < Vv; ++j) { float e = __expf(ev[j] - mx); ev[j] = e; s += e; }
        const float inv = 1.f / s;
        #pragma unroll
        for (int j = 0; j < Vv; ++j) attT[p][j][i] = ev[j] * inv;
    }
    __syncthreads();

    // ---- Phase E: h'[i][f] = sum_j att[i][j]*h[j][f]; f-major acc -> direct store ----
    if (vg < 7) {
        const int i0 = v0;                          // i-tile (4 wide)
        float4 acc0{0,0,0,0}, acc1{0,0,0,0}, acc2{0,0,0,0}, acc3{0,0,0,0};
        for (int j = 0; j < Vv; ++j) {
            const float4 at = *(const float4*)&attT[p][j][i0];   // over i
            const float4 hv = *(const float4*)&hs[p][j][f4 * 4]; // over f
            acc0.x += hv.x * at.x; acc0.y += hv.x * at.y; acc0.z += hv.x * at.z; acc0.w += hv.x * at.w;
            acc1.x += hv.y * at.x; acc1.y += hv.y * at.y; acc1.z += hv.y * at.z; acc1.w += hv.y * at.w;
            acc2.x += hv.z * at.x; acc2.y += hv.z * at.y; acc2.z += hv.z * at.z; acc2.w += hv.z * at.w;
            acc3.x += hv.w * at.x; acc3.y += hv.w * at.y; acc3.z += hv.w * at.z; acc3.w += hv.w * at.w;
        }
        const int t = t0 + p;
        float* orow = out + ((size_t)(n * Ff + f4 * 4) * Tt + t) * Vv;
        float accs[4][4] = {
            {acc0.x, acc0.y, acc0.z, acc0.w},
            {acc1.x, acc1.y, acc1.z, acc1.w},
            {acc2.x, acc2.y, acc2.z, acc2.w},
            {acc3.x, acc3.y, acc3.z, acc3.w}};
        #pragma unroll
        for (int kf = 0; kf < 4; ++kf) {
            #pragma unroll
            for (int ci = 0; ci < 4; ++ci) {
                int i = i0 + ci;
                if (i < Vv) {
                    float v = accs[kf][ci];
                    v = (v > 0.f) ? v : expm1f(v);   // elu
                    orow[(size_t)kf * Tt * Vv + i] = v;
                }
            }
        }
    }
}

extern "C" void kernel_launch(void* const* d_in, const int* in_sizes, int n_in,
                              void* d_out, int out_size, void* d_ws, size_t ws_size,
                              hipStream_t stream) {
    const float* x   = (const float*)d_in[0];
    const int*   adj = (const int*)d_in[1];
    const float* W   = (const float*)d_in[2];
    const float* a   = (const float*)d_in[3];
    float* out = (float*)d_out;

    dim3 grid(Nn * TP);     // 64 * 150 = 9600 blocks, 2 (n,t) problems each
    dim3 block(256);
    gat_kernel<<<grid, block, 0, stream>>>(x, adj, W, a, out);
}

// Round 3
// 303.999 us; speedup vs baseline: 4.3970x; 4.3970x over previous
//
#include <hip/hip_runtime.h>
#include <math.h>

constexpr int Nn = 64, Cc = 64, Tt = 300, Vv = 25, Ff = 64;
constexpr int TP = Tt / 2;   // 150 t-pairs per n
constexpr int VP = 28;       // V padded to multiple of 4
constexpr int HS = 68;       // hs row stride: 68 % 32 == 4 -> conflict-light
constexpr float ALPHA = 0.2f;
constexpr float NEG_INF = -9.0e15f;

__global__ __launch_bounds__(256, 3) void gat_kernel(
    const float* __restrict__ x,    // (N,C,T,V)
    const int*   __restrict__ adj,  // (V,V)
    const float* __restrict__ W,    // (C,F)
    const float* __restrict__ a,    // (2F,1)
    float* __restrict__ out)        // (N,F,T,V)
{
    __shared__ float Ws[Cc][Ff];          // 16384 B
    __shared__ float xs_hp[2][Cc][VP];    // 14336 B: xs (phase B) then hp (E/F)
    __shared__ float hs[2][VP][HS];       // 15232 B
    __shared__ float attT[2][Vv][VP];     // 5600 B (att transposed [j][i])
    __shared__ float f1s[2][Vv], f2s[2][Vv];
    __shared__ float a1s[Ff], a2s[Ff];
    __shared__ unsigned adjm[Vv];

    const int tid = threadIdx.x;
    const int blk = blockIdx.x;           // n*TP + tp
    const int n = blk / TP, tp = blk - n * TP;
    const int t0 = tp * 2;

    // ---- staging ----
    {   // W: 1024 float4, 4 iters, fully coalesced
        const float4* W4 = (const float4*)W;
        float4* Ws4 = (float4*)&Ws[0][0];
        #pragma unroll
        for (int i = 0; i < 4; ++i) Ws4[i * 256 + tid] = W4[i * 256 + tid];
    }
    {   // x: 64 threads per c-row of 50 contiguous floats; no div/mod
        const float* xb = x + (size_t)n * Cc * Tt * Vv + (size_t)t0 * Vv;
        const int j = tid & 63, cg = tid >> 6;
        const int pp = (j >= Vv) ? 1 : 0;
        const int v  = j - Vv * pp;
        if (j < 2 * Vv) {
            #pragma unroll
            for (int i = 0; i < 16; ++i) {
                int c = i * 4 + cg;
                xs_hp[pp][c][v] = xb[(size_t)c * (Tt * Vv) + j];
            }
        }
    }
    if (tid < Ff) { a1s[tid] = a[tid]; a2s[tid] = a[Ff + tid]; }
    else if (tid >= 128 && tid < 128 + Vv) {
        int i = tid - 128; unsigned m = 0;
        for (int j = 0; j < Vv; ++j) m |= (adj[i * Vv + j] > 0 ? 1u : 0u) << j;
        adjm[i] = m;
    }
    __syncthreads();

    const int p  = tid >> 7;        // problem 0/1 (t = t0+p)
    const int l  = tid & 127;
    const int f4 = l & 15;          // f-tile: 4 floats at 4*f4
    const int vg = l >> 4;          // 0..7; vg<7 active
    const int v0 = vg * 4;

    // ---- Phase B: h[v][f] = sum_c x[c][v]*W[c][f]; 4v x 4f per thread ----
    if (vg < 7) {
        float4 acc0{0,0,0,0}, acc1{0,0,0,0}, acc2{0,0,0,0}, acc3{0,0,0,0};
        for (int c = 0; c < Cc; ++c) {
            const float4 w  = *(const float4*)&Ws[c][f4 * 4];
            const float4 xv = *(const float4*)&xs_hp[p][c][v0];
            acc0.x += xv.x * w.x; acc0.y += xv.x * w.y; acc0.z += xv.x * w.z; acc0.w += xv.x * w.w;
            acc1.x += xv.y * w.x; acc1.y += xv.y * w.y; acc1.z += xv.y * w.z; acc1.w += xv.y * w.w;
            acc2.x += xv.z * w.x; acc2.y += xv.z * w.y; acc2.z += xv.z * w.z; acc2.w += xv.z * w.w;
            acc3.x += xv.w * w.x; acc3.y += xv.w * w.y; acc3.z += xv.w * w.z; acc3.w += xv.w * w.w;
        }
        *(float4*)&hs[p][v0 + 0][f4 * 4] = acc0;
        *(float4*)&hs[p][v0 + 1][f4 * 4] = acc1;
        *(float4*)&hs[p][v0 + 2][f4 * 4] = acc2;
        *(float4*)&hs[p][v0 + 3][f4 * 4] = acc3;
    }
    __syncthreads();

    // ---- Phase C: f1[i]=h[i,:]·a1, f2[i]=h[i,:]·a2 ----
    if (l < 2 * Vv) {
        const int i = (l < Vv) ? l : l - Vv;
        const float* av = (l < Vv) ? a1s : a2s;
        float s = 0.f;
        #pragma unroll
        for (int q = 0; q < Ff / 4; ++q) {
            float4 h4 = *(const float4*)&hs[p][i][q * 4];
            float4 a4 = *(const float4*)&av[q * 4];
            s += h4.x * a4.x + h4.y * a4.y + h4.z * a4.z + h4.w * a4.w;
        }
        if (l < Vv) f1s[p][i] = s; else f2s[p][i] = s;
    }
    __syncthreads();

    // ---- Phase D: masked leaky-relu + softmax; write attT[j][i] ----
    if (l < Vv) {
        const int i = l;
        const float fi = f1s[p][i];
        const unsigned m = adjm[i];
        float ev[Vv];
        float mx = -INFINITY;
        #pragma unroll
        for (int j = 0; j < Vv; ++j) {
            float z = fi + f2s[p][j];
            z = (z > 0.f) ? z : ALPHA * z;         // leaky_relu BEFORE mask
            z = ((m >> j) & 1u) ? z : NEG_INF;
            ev[j] = z; mx = fmaxf(mx, z);
        }
        float s = 0.f;
        #pragma unroll
        for (int j = 0; j < Vv; ++j) { float e = __expf(ev[j] - mx); ev[j] = e; s += e; }
        const float inv = 1.f / s;
        #pragma unroll
        for (int j = 0; j < Vv; ++j) attT[p][j][i] = ev[j] * inv;
    }
    __syncthreads();

    // ---- Phase E: h'[i][f] = sum_j att[i][j]*h[j][f]; elu; stage to hp LDS ----
    if (vg < 7) {
        const int i0 = v0;
        float4 acc[4] = {};                         // acc[kf] spans i0..i0+3
        for (int j = 0; j < Vv; ++j) {
            const float4 at = *(const float4*)&attT[p][j][i0];
            const float4 hv = *(const float4*)&hs[p][j][f4 * 4];
            acc[0].x += hv.x * at.x; acc[0].y += hv.x * at.y; acc[0].z += hv.x * at.z; acc[0].w += hv.x * at.w;
            acc[1].x += hv.y * at.x; acc[1].y += hv.y * at.y; acc[1].z += hv.y * at.z; acc[1].w += hv.y * at.w;
            acc[2].x += hv.z * at.x; acc[2].y += hv.z * at.y; acc[2].z += hv.z * at.z; acc[2].w += hv.z * at.w;
            acc[3].x += hv.w * at.x; acc[3].y += hv.w * at.y; acc[3].z += hv.w * at.z; acc[3].w += hv.w * at.w;
        }
        #pragma unroll
        for (int kf = 0; kf < 4; ++kf) {
            float4 v = acc[kf];
            // elu(alpha=1): expf(v)-1 for v<=0 (abs err ~1e-7, threshold 7.25e-2)
            v.x = (v.x > 0.f) ? v.x : (__expf(v.x) - 1.f);
            v.y = (v.y > 0.f) ? v.y : (__expf(v.y) - 1.f);
            v.z = (v.z > 0.f) ? v.z : (__expf(v.z) - 1.f);
            v.w = (v.w > 0.f) ? v.w : (__expf(v.w) - 1.f);
            *(float4*)&xs_hp[p][f4 * 4 + kf][i0] = v;   // hp[f][i]
        }
    }
    __syncthreads();

    // ---- Phase F: contiguous writeout out[n,f,t,i] from hp ----
    {
        const int i  = tid & 31;          // 0..31, active i<25
        const int fr = tid >> 5;          // 0..7
        if (i < Vv) {
            #pragma unroll
            for (int pp = 0; pp < 2; ++pp) {
                float* ob = out + ((size_t)n * Ff * Tt + (size_t)(t0 + pp)) * Vv;
                #pragma unroll
                for (int fb = 0; fb < 8; ++fb) {
                    int f = fb * 8 + fr;
                    ob[(size_t)f * Tt * Vv + i] = xs_hp[pp][f][i];
                }
            }
        }
    }
}

extern "C" void kernel_launch(void* const* d_in, const int* in_sizes, int n_in,
                              void* d_out, int out_size, void* d_ws, size_t ws_size,
                              hipStream_t stream) {
    const float* x   = (const float*)d_in[0];
    const int*   adj = (const int*)d_in[1];
    const float* W   = (const float*)d_in[2];
    const float* a   = (const float*)d_in[3];
    float* out = (float*)d_out;

    dim3 grid(Nn * TP);     // 9600 blocks, 2 (n,t) problems each
    dim3 block(256);
    gat_kernel<<<grid, block, 0, stream>>>(x, adj, W, a, out);
}